// Round 5
// baseline (10238.873 us; speedup 1.0000x reference)
//
#include <hip/hip_runtime.h>

// ---------------- problem constants ----------------
#define B_  64
#define S_  512
#define L_  16
#define WD_ 200
#define CD_ 30
#define FN_ 4
#define KW_ 3
#define H_  256
#define T_  17
#define D_  320   // WD + CD*FN

typedef unsigned short ushort_t;
typedef unsigned long long u64_t;
typedef __attribute__((ext_vector_type(8))) short v8s;   // bf16x8 MFMA frag
typedef __attribute__((ext_vector_type(4))) float v4f;   // fp32x4 MFMA acc
typedef __attribute__((ext_vector_type(4))) float f4;
typedef __attribute__((ext_vector_type(4))) unsigned int ui4;
typedef __attribute__((ext_vector_type(4))) unsigned short us4;

__device__ __forceinline__ float bf2f(unsigned short u) {
  union { unsigned int i; float f; } v; v.i = ((unsigned int)u) << 16; return v.f;
}
__device__ __forceinline__ unsigned short f2bf(float f) {
  union { float f; unsigned int i; } v; v.f = f;
  unsigned int r = v.i + 0x7fffu + ((v.i >> 16) & 1u);   // RNE
  return (unsigned short)(r >> 16);
}

// ---------------- K1: word emb (f32->bf16) + char CNN + maxpool -> z [B*S, 320] bf16 ----------------
__global__ __launch_bounds__(64) void k_embed(
    const int* __restrict__ tok, const int* __restrict__ ctok,
    const float* __restrict__ wemb, const float* __restrict__ cemb,
    const float* __restrict__ cw, const float* __restrict__ cb,
    ushort_t* __restrict__ z)
{
  int w = blockIdx.x;           // word index = b*S + s
  int l = threadIdx.x;
  __shared__ float ce[L_][32];  // char embeddings fp32
  if (l < L_) {
    int cid = ctok[w * L_ + l];
    const float* row = cemb + (size_t)cid * CD_;
    #pragma unroll
    for (int j = 0; j < CD_; ++j) ce[l][j] = row[j];
  }
  int t = tok[w];
  const f4* src = (const f4*)(wemb + (size_t)t * WD_);
  if (l < 50) {
    f4 v = src[l];
    us4 o; o[0]=f2bf(v[0]); o[1]=f2bf(v[1]); o[2]=f2bf(v[2]); o[3]=f2bf(v[3]);
    *(us4*)(z + (size_t)w * D_ + l*4) = o;
  }
  __syncthreads();
  for (int oc = l; oc < CD_ * FN_; oc += 64) {
    int c = oc >> 2;
    float w0 = cw[oc*3+0], w1 = cw[oc*3+1], w2 = cw[oc*3+2];
    float mx = -3e30f;
    #pragma unroll
    for (int p = 0; p < L_ - KW_ + 1; ++p) {
      float s = ce[p][c]*w0 + ce[p+1][c]*w1 + ce[p+2][c]*w2;
      mx = fmaxf(mx, s);
    }
    z[(size_t)w * D_ + WD_ + oc] = f2bf(mx + cb[oc]);
  }
}

// ---------------- K2: gx2 = z @ W_ih^T, stored in LSTM-lane-slot order --------------------------
// gx2[dir][s][ (g*16 + cb*4 + w)*64 + lane ][16]  where [16] = gate*4 + r (bf16)
__global__ __launch_bounds__(256) void k_gemm_gx(
    const ushort_t* __restrict__ z, const float* __restrict__ wf,
    const float* __restrict__ wb, ushort_t* __restrict__ gx2)
{
  __shared__ ushort_t As[128 * 40];
  __shared__ ushort_t Bs[64 * 40];
  int m0 = blockIdx.x * 128;
  int n0g = blockIdx.y * 64;
  int dir = n0g >> 10;
  int ncol0 = n0g & 1023;
  const float* W = dir ? wb : wf;
  int tid = threadIdx.x;
  int wv = tid >> 6, l = tid & 63;
  int lm = l & 15, lq = l >> 4;
  v4f acc[2][4];
  #pragma unroll
  for (int i = 0; i < 2; i++)
    #pragma unroll
    for (int j = 0; j < 4; j++) acc[i][j] = (v4f)0.f;

  for (int kc = 0; kc < 10; ++kc) {
    int k0 = kc * 32;
    #pragma unroll
    for (int rep = 0; rep < 2; ++rep) {
      int idx = rep * 256 + tid;
      int row = idx >> 2, q = idx & 3;
      *(ui4*)(As + row*40 + q*8) =
          *(const ui4*)(z + (size_t)(m0 + row)*D_ + k0 + q*8);
    }
    {
      int row = tid >> 2, q = tid & 3;
      const float* src = W + (size_t)(ncol0 + row)*D_ + k0 + q*8;
      f4 a = *(const f4*)src, b2 = *(const f4*)(src + 4);
      us4 o0, o1;
      o0[0]=f2bf(a[0]); o0[1]=f2bf(a[1]); o0[2]=f2bf(a[2]); o0[3]=f2bf(a[3]);
      o1[0]=f2bf(b2[0]); o1[1]=f2bf(b2[1]); o1[2]=f2bf(b2[2]); o1[3]=f2bf(b2[3]);
      *(us4*)(Bs + row*40 + q*8) = o0;
      *(us4*)(Bs + row*40 + q*8 + 4) = o1;
    }
    __syncthreads();
    v8s a0 = *(const v8s*)(As + (wv*32 + lm)*40 + lq*8);
    v8s a1 = *(const v8s*)(As + (wv*32 + 16 + lm)*40 + lq*8);
    #pragma unroll
    for (int nt = 0; nt < 4; ++nt) {
      v8s b = *(const v8s*)(Bs + (nt*16 + lm)*40 + lq*8);
      acc[0][nt] = __builtin_amdgcn_mfma_f32_16x16x32_bf16(a0, b, acc[0][nt], 0, 0, 0);
      acc[1][nt] = __builtin_amdgcn_mfma_f32_16x16x32_bf16(a1, b, acc[1][nt], 0, 0, 0);
    }
    __syncthreads();
  }
  // epilogue: scatter into gx2 lane-slot layout
  #pragma unroll
  for (int mt = 0; mt < 2; mt++)
    #pragma unroll
    for (int nt = 0; nt < 4; nt++)
      #pragma unroll
      for (int r = 0; r < 4; r++) {
        int m = m0 + wv*32 + mt*16 + lq*4 + r;     // z row = b*512 + s
        int col = ncol0 + nt*16 + lm;              // gate-row 0..1023
        int b = m >> 9, s = m & 511;
        int gate = col >> 8, unit = col & 255;
        int cbx = unit >> 6, wx = (unit >> 4) & 3, lmx = unit & 15;
        int gsx = b >> 4, lqx = (b >> 2) & 3, rx = b & 3;
        gx2[(size_t)(dir*512 + s)*65536
            + (size_t)((gsx*16 + cbx*4 + wx)*64 + lqx*16 + lmx)*16
            + gate*4 + rx] = f2bf(acc[mt][nt][r]);
      }
}

// ---------------- K3: fence-free persistent-weight bidirectional LSTM --------------------------
// 8 blocks: dir(2) x unit-block(4, 64 units). Wave w owns units [cb*64+w*16, +16) for ALL 4 gates
// (nt = gate) -> combine is in-wave, no LDS/barriers. 4 batch-streams interleaved per block.
// h exchanged via u64 {2 bf16, step tag} relaxed agent atomics; consumers validate tags (no fences).
__device__ __forceinline__ void issue_h(const u64_t* __restrict__ hb, int lm, int lq,
                                        u64_t U[8][4]) {
  #pragma unroll
  for (int kc = 0; kc < 8; kc++)
    #pragma unroll
    for (int q = 0; q < 4; q++)
      U[kc][q] = __hip_atomic_load(hb + lm*128 + kc*16 + lq*4 + q,
                                   __ATOMIC_RELAXED, __HIP_MEMORY_SCOPE_AGENT);
}
__device__ __forceinline__ bool check_h(const u64_t U[8][4], unsigned int tag) {
  bool ok = true;
  #pragma unroll
  for (int kc = 0; kc < 8; kc++)
    #pragma unroll
    for (int q = 0; q < 4; q++)
      ok = ok && ((unsigned int)(U[kc][q] >> 32) == tag);
  return ok;
}

__global__ __launch_bounds__(256, 1) void k_lstm(
    const ushort_t* __restrict__ gx2,
    const float* __restrict__ whhf, const float* __restrict__ whhb,
    const float* __restrict__ bf_, const float* __restrict__ bb_,
    u64_t* __restrict__ hb64, ushort_t* __restrict__ hs)
{
  int bid = blockIdx.x;
  int dir = bid >> 2, cb = bid & 3;
  int tid = threadIdx.x, w = tid >> 6, l = tid & 63;
  int lm = l & 15, lq = l >> 4;
  int ub = cb*64 + w*16;                 // + lm = unit
  const float* W = dir ? whhb : whhf;
  const float* bias = dir ? bb_ : bf_;
  // persistent weights: nt = gate, rows gate*256 + ub + lm  (4 x 8 x v8s = 128 VGPR)
  v8s wfr[4][8];
  #pragma unroll
  for (int nt = 0; nt < 4; nt++)
    #pragma unroll
    for (int kc = 0; kc < 8; kc++) {
      const float* src = W + (size_t)(nt*256 + ub + lm)*256 + kc*32 + lq*8;
      f4 a = *(const f4*)src, b2 = *(const f4*)(src + 4);
      v8s f;
      f[0]=(short)f2bf(a[0]); f[1]=(short)f2bf(a[1]); f[2]=(short)f2bf(a[2]); f[3]=(short)f2bf(a[3]);
      f[4]=(short)f2bf(b2[0]); f[5]=(short)f2bf(b2[1]); f[6]=(short)f2bf(b2[2]); f[7]=(short)f2bf(b2[3]);
      wfr[nt][kc] = f;
    }
  float bv[4];
  #pragma unroll
  for (int nt = 0; nt < 4; nt++) bv[nt] = bias[nt*256 + ub + lm];

  float c[4][4];                         // [stream][r] cell state, fp32
  #pragma unroll
  for (int g = 0; g < 4; g++)
    #pragma unroll
    for (int r = 0; r < 4; r++) c[g][r] = 0.f;

  u64_t U[2][8][4];                      // ping-pong h buffers (128 VGPR)
  u64_t* hbD = hb64 + (size_t)dir * 4 * 2 * 2048;   // per (dir): [g][parity][2048]

  // initial prefetch: slot (n=0, g=0), parity 1, tag 0 (memset zeros)
  issue_h(hbD + (size_t)(0*2 + 1)*2048, lm, lq, U[0]);

  for (int n = 0; n < 512; ++n) {
    int t = dir ? (511 - n) : n;
    const ushort_t* gbase = gx2 + (size_t)(dir*512 + t)*65536
                          + (size_t)((cb*4 + w)*64 + l)*16;
    unsigned int tag = (unsigned int)n;          // expect h_{n-1}
    unsigned int wtag = (unsigned int)(n + 1);   // write h_n
    int rp = (n & 1) ^ 1;                        // read parity
    #pragma unroll
    for (int g = 0; g < 4; ++g) {
      int buf = g & 1;
      // gx for this slot: 32B contiguous (gate nt -> us4 q[nt], elem r)
      const ushort_t* gp = gbase + (size_t)g * 16384;
      us4 q0 = *(const us4*)(gp);
      us4 q1 = *(const us4*)(gp + 4);
      us4 q2 = *(const us4*)(gp + 8);
      us4 q3 = *(const us4*)(gp + 12);
      // validate current stream's h (retry-reload on tag mismatch)
      {
        const u64_t* hrd = hbD + ((size_t)g*2 + rp)*2048;
        bool ok = check_h(U[buf], tag);
        int guard = 0;
        while (!__all(ok)) {
          issue_h(hrd, lm, lq, U[buf]);
          ok = check_h(U[buf], tag);
          if (++guard > (1 << 22)) break;        // safety valve
        }
      }
      // prefetch next slot's h into the other buffer (overlaps with MFMA below)
      if (!(n == 511 && g == 3)) {
        int n2 = (g < 3) ? n : n + 1;
        int g2 = (g < 3) ? g + 1 : 0;
        const u64_t* hpf = hbD + ((size_t)g2*2 + ((n2 & 1) ^ 1))*2048;
        issue_h(hpf, lm, lq, U[buf ^ 1]);
      }
      // MFMA: gates[nt] for 16 units x 4 batches
      v4f acc[4];
      #pragma unroll
      for (int nt = 0; nt < 4; nt++) acc[nt] = (v4f)0.f;
      #pragma unroll
      for (int kc = 0; kc < 8; kc++) {
        v8s af;
        #pragma unroll
        for (int qq = 0; qq < 4; qq++) {
          unsigned int h01 = (unsigned int)U[buf][kc][qq];
          af[2*qq]   = (short)(h01 & 0xffffu);
          af[2*qq+1] = (short)(h01 >> 16);
        }
        #pragma unroll
        for (int nt = 0; nt < 4; nt++)
          acc[nt] = __builtin_amdgcn_mfma_f32_16x16x32_bf16(af, wfr[nt][kc], acc[nt], 0, 0, 0);
      }
      // combine in-wave (lane owns unit ub+lm, batches lq*4+r of stream g)
      u64_t* hwr = hbD + ((size_t)g*2 + (n & 1))*2048;
      #pragma unroll
      for (int r = 0; r < 4; r++) {
        float pi = acc[0][r] + bf2f(q0[r]) + bv[0];
        float pf = acc[1][r] + bf2f(q1[r]) + bv[1];
        float pg = acc[2][r] + bf2f(q2[r]) + bv[2];
        float po = acc[3][r] + bf2f(q3[r]) + bv[3];
        float ii = 1.f / (1.f + expf(-pi));
        float ff = 1.f / (1.f + expf(-pf));
        float gg = tanhf(pg);
        float oo = 1.f / (1.f + expf(-po));
        c[g][r] = ff * c[g][r] + ii * gg;
        float h = oo * tanhf(c[g][r]);
        unsigned int hv = (unsigned int)f2bf(h);
        unsigned int pv = (unsigned int)__shfl_xor((int)hv, 1);
        if (!(l & 1)) {
          u64_t pk = ((u64_t)wtag << 32) | (pv << 16) | hv;
          __hip_atomic_store(&hwr[(size_t)(lq*4 + r)*128 + ((ub + lm) >> 1)], pk,
                             __ATOMIC_RELAXED, __HIP_MEMORY_SCOPE_AGENT);
        }
        hs[((size_t)(dir*512 + t)*64 + g*16 + lq*4 + r)*256 + ub + lm] = (ushort_t)hv;
      }
    }
  }
}

// ---------------- K4: emissions[b][s][17] = [h_f, h_b] @ cls_w^T + cls_b (fp32) ----------------
__global__ __launch_bounds__(256) void k_emis(
    const ushort_t* __restrict__ hs, const float* __restrict__ clsw,
    const float* __restrict__ clsb, float* __restrict__ emis)
{
  int tid = threadIdx.x;
  if (tid >= 255) return;
  int wi = blockIdx.x * 15 + tid / 17;
  int tau = tid % 17;
  if (wi >= B_ * S_) return;
  int b = wi >> 9, s = wi & 511;
  const ushort_t* hf  = hs + ((size_t)s*64 + b) * 256;
  const ushort_t* hbk = hs + (((size_t)512 + s)*64 + b) * 256;
  const float* cwf = clsw + (size_t)tau * 512;
  const float* cwb = cwf + 256;
  union { unsigned int u; float f; } bc;
  float acc = clsb[tau];
  for (int k = 0; k < 256; k += 4) {
    us4 h4 = *(const us4*)(hf + k); f4 w4 = *(const f4*)(cwf + k);
    #pragma unroll
    for (int j = 0; j < 4; j++) { bc.u = (unsigned int)h4[j] << 16; acc += bc.f * w4[j]; }
  }
  for (int k = 0; k < 256; k += 4) {
    us4 h4 = *(const us4*)(hbk + k); f4 w4 = *(const f4*)(cwb + k);
    #pragma unroll
    for (int j = 0; j < 4; j++) { bc.u = (unsigned int)h4[j] << 16; acc += bc.f * w4[j]; }
  }
  emis[(size_t)wi * 17 + tau] = acc;
}

// ---------------- K5/K6: CRF loss forward (blocks 0..15) + Viterbi (blocks 16..31) -------------
__global__ __launch_bounds__(256) void k_crf(
    const float* __restrict__ emis, const int* __restrict__ labels,
    const int* __restrict__ mask, const float* __restrict__ startt,
    const float* __restrict__ endt, const float* __restrict__ trans,
    float* __restrict__ lossp, float* __restrict__ outp)
{
  __shared__ unsigned char bps[4][511][17];
  int blk = blockIdx.x;
  int tid = threadIdx.x, wv = tid >> 6, l = tid & 63;
  bool isv = blk >= 16;
  int b = (blk & 15) * 4 + wv;
  int tauc = (l < 17) ? l : 0;
  float tc[17];
  #pragma unroll
  for (int i = 0; i < 17; i++) tc[i] = trans[i*17 + tauc];
  const float* eb = emis + (size_t)b * 512 * 17;
  float alpha = startt[tauc] + eb[tauc];
  if (l >= 17) alpha = -3e30f;

  if (!isv) {
    for (int t = 1; t < 512; t++) {
      float e = (l < 17) ? eb[t*17 + l] : 0.f;
      int mt = mask[b*512 + t];
      float arr[17]; float mx = -3e30f;
      #pragma unroll
      for (int i = 0; i < 17; i++) {
        float av = __shfl(alpha, i);
        arr[i] = av + tc[i];
        mx = fmaxf(mx, arr[i]);
      }
      float ss = 0.f;
      #pragma unroll
      for (int i = 0; i < 17; i++) ss += expf(arr[i] - mx);
      float nxt = mx + logf(ss) + e;
      if (mt > 0 && l < 17) alpha = nxt;
    }
    float a2 = (l < 17) ? (alpha + endt[l]) : -3e30f;
    float mx = a2;
    #pragma unroll
    for (int o = 32; o > 0; o >>= 1) mx = fmaxf(mx, __shfl_xor(mx, o));
    float ss = (l < 17) ? expf(a2 - mx) : 0.f;
    #pragma unroll
    for (int o = 32; o > 0; o >>= 1) ss += __shfl_xor(ss, o);
    float denom = mx + logf(ss);
    float ns = 0.f; int msum = 0;
    for (int t = l; t < 512; t += 64) {
      int tg = labels[b*512 + t];
      int mt = mask[b*512 + t];
      msum += (mt > 0);
      if (mt > 0) {
        ns += eb[t*17 + tg];
        if (t > 0) ns += trans[labels[b*512 + t - 1]*17 + tg];
      }
    }
    #pragma unroll
    for (int o = 32; o > 0; o >>= 1) { ns += __shfl_xor(ns, o); msum += __shfl_xor(msum, o); }
    if (l == 0) {
      int lidx = msum - 1;
      float num = ns + startt[labels[b*512]] + endt[labels[b*512 + lidx]];
      lossp[b] = num - denom;
    }
  } else {
    for (int t = 1; t < 512; t++) {
      float e = (l < 17) ? eb[t*17 + l] : 0.f;
      int mt = mask[b*512 + t];
      float best = -3e30f; int bi = 0;
      #pragma unroll
      for (int i = 0; i < 17; i++) {
        float v = __shfl(alpha, i) + tc[i];
        if (v > best) { best = v; bi = i; }
      }
      float nxt = best + e;
      int bpv = (mt > 0) ? bi : l;
      if (l < 17) {
        bps[wv][t-1][l] = (unsigned char)bpv;
        if (mt > 0) alpha = nxt;
      }
    }
    __syncthreads();
    float a2 = (l < 17) ? (alpha + endt[l]) : -3e30f;
    float av[17];
    #pragma unroll
    for (int i = 0; i < 17; i++) av[i] = __shfl(a2, i);
    int bt = 0; float bv2 = av[0];
    #pragma unroll
    for (int i = 1; i < 17; i++) if (av[i] > bv2) { bv2 = av[i]; bt = i; }
    if (l == 0) outp[1 + b*512 + 511] = (float)bt;
    int tg = bt;
    for (int t = 510; t >= 0; --t) {
      tg = bps[wv][t][tg];
      if (l == 0) outp[1 + b*512 + t] = (float)tg;
    }
  }
}

// ---------------- K7: loss = -mean(num - denom), fp32 ----------------
__global__ __launch_bounds__(64) void k_final(const float* __restrict__ lossp,
                                              float* __restrict__ outp)
{
  int l = threadIdx.x;
  float v = lossp[l];
  #pragma unroll
  for (int o = 32; o > 0; o >>= 1) v += __shfl_xor(v, o);
  if (l == 0) outp[0] = -(v / 64.f);
}

// ---------------- host ----------------
extern "C" void kernel_launch(void* const* d_in, const int* in_sizes, int n_in,
                              void* d_out, int out_size, void* d_ws, size_t ws_size,
                              hipStream_t stream)
{
  (void)in_sizes; (void)n_in; (void)out_size; (void)ws_size;
  const int*   tok   = (const int*)d_in[0];
  const int*   ctok  = (const int*)d_in[1];
  const int*   labels= (const int*)d_in[2];
  const int*   amask = (const int*)d_in[3];
  const float* wemb  = (const float*)d_in[4];
  const float* cemb  = (const float*)d_in[5];
  const float* convw = (const float*)d_in[6];
  const float* convb = (const float*)d_in[7];
  const float* wihf  = (const float*)d_in[8];
  const float* whhf  = (const float*)d_in[9];
  const float* bfv   = (const float*)d_in[10];
  const float* wihb  = (const float*)d_in[11];
  const float* whhb  = (const float*)d_in[12];
  const float* bbv   = (const float*)d_in[13];
  const float* clsw  = (const float*)d_in[14];
  const float* clsb  = (const float*)d_in[15];
  const float* stt   = (const float*)d_in[16];
  const float* ent   = (const float*)d_in[17];
  const float* trn   = (const float*)d_in[18];

  // workspace layout (bytes):
  // [pad 512][hb64 262144][z 20,971,520][gx2 134,217,728][hs 33,554,432][emis 2,228,224][lossp 256]
  char* ws = (char*)d_ws;
  u64_t*    hb64 = (u64_t*)(ws + 512);
  ushort_t* z    = (ushort_t*)(ws + 262656);
  ushort_t* gx2  = (ushort_t*)(ws + 21234176);
  ushort_t* hs   = (ushort_t*)(ws + 155451904);
  float*    emis = (float*)(ws + 189006336);
  float*    lossp= (float*)(ws + 191234560);

  // zero h exchange buffers (h_{-1}=0, tag 0) — every launch (ws re-poisoned)
  hipMemsetAsync(ws, 0, 262656, stream);

  hipLaunchKernelGGL(k_embed,   dim3(B_*S_),       dim3(64),  0, stream,
                     tok, ctok, wemb, cemb, convw, convb, z);
  hipLaunchKernelGGL(k_gemm_gx, dim3(256, 32),     dim3(256), 0, stream,
                     z, wihf, wihb, gx2);
  hipLaunchKernelGGL(k_lstm,    dim3(8),           dim3(256), 0, stream,
                     gx2, whhf, whhb, bfv, bbv, hb64, hs);
  hipLaunchKernelGGL(k_emis,    dim3((B_*S_ + 14)/15), dim3(256), 0, stream,
                     hs, clsw, clsb, emis);
  hipLaunchKernelGGL(k_crf,     dim3(32),          dim3(256), 0, stream,
                     emis, labels, amask, stt, ent, trn, lossp, (float*)d_out);
  hipLaunchKernelGGL(k_final,   dim3(1),           dim3(64),  0, stream,
                     lossp, (float*)d_out);
}

// Round 6
// 4058.427 us; speedup vs baseline: 2.5229x; 2.5229x over previous
//
#include <hip/hip_runtime.h>

// ---------------- problem constants ----------------
#define B_  64
#define S_  512
#define L_  16
#define WD_ 200
#define CD_ 30
#define FN_ 4
#define KW_ 3
#define H_  256
#define T_  17
#define D_  320   // WD + CD*FN
#define PITCH_H 264

typedef unsigned short ushort_t;
typedef __attribute__((ext_vector_type(8))) short v8s;   // bf16x8 MFMA frag
typedef __attribute__((ext_vector_type(4))) float v4f;   // fp32x4 MFMA acc
typedef __attribute__((ext_vector_type(4))) float f4;
typedef __attribute__((ext_vector_type(4))) unsigned int ui4;
typedef __attribute__((ext_vector_type(4))) unsigned short us4;

__device__ __forceinline__ float bf2f(unsigned short u) {
  union { unsigned int i; float f; } v; v.i = ((unsigned int)u) << 16; return v.f;
}
__device__ __forceinline__ unsigned short f2bf(float f) {
  union { float f; unsigned int i; } v; v.f = f;
  unsigned int r = v.i + 0x7fffu + ((v.i >> 16) & 1u);   // RNE
  return (unsigned short)(r >> 16);
}
__device__ __forceinline__ float sigm(float x) {
  return __fdividef(1.f, 1.f + __expf(-x));
}
__device__ __forceinline__ float tanhp(float x) {
  float e = __expf(2.f * x);
  return __fdividef(e - 1.f, e + 1.f);
}
// barrier that does NOT drain vmcnt (keeps global prefetch loads in flight)
__device__ __forceinline__ void block_sync_lds() {
  __asm__ volatile("s_waitcnt lgkmcnt(0)\n\ts_barrier" ::: "memory");
}

// ---------------- K1: word emb (f32->bf16) + char CNN + maxpool -> z [B*S, 320] bf16 ----------------
__global__ __launch_bounds__(64) void k_embed(
    const int* __restrict__ tok, const int* __restrict__ ctok,
    const float* __restrict__ wemb, const float* __restrict__ cemb,
    const float* __restrict__ cw, const float* __restrict__ cb,
    ushort_t* __restrict__ z)
{
  int w = blockIdx.x;
  int l = threadIdx.x;
  __shared__ float ce[L_][32];
  if (l < L_) {
    int cid = ctok[w * L_ + l];
    const float* row = cemb + (size_t)cid * CD_;
    #pragma unroll
    for (int j = 0; j < CD_; ++j) ce[l][j] = row[j];
  }
  int t = tok[w];
  const f4* src = (const f4*)(wemb + (size_t)t * WD_);
  if (l < 50) {
    f4 v = src[l];
    us4 o; o[0]=f2bf(v[0]); o[1]=f2bf(v[1]); o[2]=f2bf(v[2]); o[3]=f2bf(v[3]);
    *(us4*)(z + (size_t)w * D_ + l*4) = o;
  }
  __syncthreads();
  for (int oc = l; oc < CD_ * FN_; oc += 64) {
    int c = oc >> 2;
    float w0 = cw[oc*3+0], w1 = cw[oc*3+1], w2 = cw[oc*3+2];
    float mx = -3e30f;
    #pragma unroll
    for (int p = 0; p < L_ - KW_ + 1; ++p) {
      float s = ce[p][c]*w0 + ce[p+1][c]*w1 + ce[p+2][c]*w2;
      mx = fmaxf(mx, s);
    }
    z[(size_t)w * D_ + WD_ + oc] = f2bf(mx + cb[oc]);
  }
}

// ---------------- K2: gx2 = z @ W_ih^T + b, packed per (dir,s,bg,group) as 1KB blocks ------------
// gx2 idx = ((dir*512+s)*8+bg)*8192 + gr*512 + (lq*16+lm)*16 + gate*4 + r   (bf16)
__global__ __launch_bounds__(256) void k_gemm_gx(
    const ushort_t* __restrict__ z, const float* __restrict__ wf,
    const float* __restrict__ wb, const float* __restrict__ bfv,
    const float* __restrict__ bbv, ushort_t* __restrict__ gx2)
{
  __shared__ ushort_t As[128 * 40];
  __shared__ ushort_t Bs[64 * 40];
  int m0 = blockIdx.x * 128;
  int n0g = blockIdx.y * 64;
  int dir = n0g >> 10;
  int ncol0 = n0g & 1023;
  const float* W = dir ? wb : wf;
  const float* bias = dir ? bbv : bfv;
  int tid = threadIdx.x;
  int wv = tid >> 6, l = tid & 63;
  int lm = l & 15, lq = l >> 4;
  v4f acc[2][4];
  #pragma unroll
  for (int i = 0; i < 2; i++)
    #pragma unroll
    for (int j = 0; j < 4; j++) acc[i][j] = (v4f)0.f;

  for (int kc = 0; kc < 10; ++kc) {
    int k0 = kc * 32;
    #pragma unroll
    for (int rep = 0; rep < 2; ++rep) {
      int idx = rep * 256 + tid;
      int row = idx >> 2, q = idx & 3;
      *(ui4*)(As + row*40 + q*8) =
          *(const ui4*)(z + (size_t)(m0 + row)*D_ + k0 + q*8);
    }
    {
      int row = tid >> 2, q = tid & 3;
      const float* src = W + (size_t)(ncol0 + row)*D_ + k0 + q*8;
      f4 a = *(const f4*)src, b2 = *(const f4*)(src + 4);
      us4 o0, o1;
      o0[0]=f2bf(a[0]); o0[1]=f2bf(a[1]); o0[2]=f2bf(a[2]); o0[3]=f2bf(a[3]);
      o1[0]=f2bf(b2[0]); o1[1]=f2bf(b2[1]); o1[2]=f2bf(b2[2]); o1[3]=f2bf(b2[3]);
      *(us4*)(Bs + row*40 + q*8) = o0;
      *(us4*)(Bs + row*40 + q*8 + 4) = o1;
    }
    __syncthreads();
    v8s a0 = *(const v8s*)(As + (wv*32 + lm)*40 + lq*8);
    v8s a1 = *(const v8s*)(As + (wv*32 + 16 + lm)*40 + lq*8);
    #pragma unroll
    for (int nt = 0; nt < 4; ++nt) {
      v8s b = *(const v8s*)(Bs + (nt*16 + lm)*40 + lq*8);
      acc[0][nt] = __builtin_amdgcn_mfma_f32_16x16x32_bf16(a0, b, acc[0][nt], 0, 0, 0);
      acc[1][nt] = __builtin_amdgcn_mfma_f32_16x16x32_bf16(a1, b, acc[1][nt], 0, 0, 0);
    }
    __syncthreads();
  }
  // epilogue with bias fold + scatter into gx2 packing
  float bval[4];
  #pragma unroll
  for (int nt = 0; nt < 4; nt++) bval[nt] = bias[ncol0 + nt*16 + lm];
  #pragma unroll
  for (int mt = 0; mt < 2; mt++)
    #pragma unroll
    for (int nt = 0; nt < 4; nt++)
      #pragma unroll
      for (int r = 0; r < 4; r++) {
        int m = m0 + wv*32 + mt*16 + lq*4 + r;
        int col = ncol0 + nt*16 + lm;
        int b = m >> 9, s = m & 511;
        int gate = col >> 8, unit = col & 255;
        int gr = unit >> 4, lm2 = unit & 15;
        int bg = b >> 3, bb = b & 7;
        int lq2 = bb >> 2, r2 = bb & 3;
        size_t idx = ((size_t)(dir*512 + s)*8 + bg)*8192
                   + gr*512 + (lq2*16 + lm2)*16 + gate*4 + r2;
        gx2[idx] = f2bf(acc[mt][nt][r] + bval[nt]);
      }
}

// ---------------- K3: intra-CU persistent LSTM — zero cross-block sync --------------------------
// 16 blocks: dir(2) x batch-group(8, B=8). Block = 512 thr = 8 waves. Wave w owns units
// [32w,32w+32) for all 4 gates: 6 W-tiles in regs (192 VGPR) + 2 in LDS. h/c in LDS.
__global__ __launch_bounds__(512, 2) void k_lstm(
    const ushort_t* __restrict__ gx2,
    const float* __restrict__ whhf, const float* __restrict__ whhb,
    ushort_t* __restrict__ hs)
{
  __shared__ ushort_t Wl[16 * 8 * 512];          // 128 KB: LDS W tiles (frag layout)
  __shared__ ushort_t hsh[2][16][PITCH_H];       // 16.5 KB: h double buffer
  __shared__ float    csh[8][256];               // 8 KB: cell state
  int bid = blockIdx.x;
  int dir = bid >> 3, bg = bid & 7;
  int tid = threadIdx.x, w = tid >> 6, l = tid & 63;
  int lm = l & 15, lq = l >> 4;
  const float* W = dir ? whhb : whhf;

  // init LDS: zero h (both parities; rows 8..15 stay 0 forever) + zero c
  for (int i = tid; i < 2 * 16 * PITCH_H; i += 512) ((ushort_t*)hsh)[i] = 0;
  for (int i = tid; i < 8 * 256; i += 512) ((float*)csh)[i] = 0.f;
  // stage LDS W tiles: tile tl = w2*2+gsel -> group 2*w2+1, gate 2+gsel
  for (int idx = tid; idx < 16 * 8 * 64; idx += 512) {
    int tl = idx >> 9, kc = (idx >> 6) & 7, ln = idx & 63;
    int lq2 = ln >> 4, lm2 = ln & 15;
    int w2 = tl >> 1, gsel = tl & 1;
    int row = (2 + gsel)*256 + (w2*2 + 1)*16 + lm2;
    const float* src = W + (size_t)row*256 + kc*32 + lq2*8;
    v8s f;
    #pragma unroll
    for (int j = 0; j < 8; j++) f[j] = (short)f2bf(src[j]);
    *(v8s*)(Wl + ((size_t)(tl*8 + kc)*64 + ln)*8) = f;
  }
  // reg W tiles: [0..3] = (group 2w, gates i,f,g,o); [4,5] = (group 2w+1, gates i,f)
  v8s wfr[6][8];
  #pragma unroll
  for (int ti = 0; ti < 6; ti++) {
    int gr = (ti < 4) ? (2*w) : (2*w + 1);
    int ga = (ti < 4) ? ti : (ti - 4);
    #pragma unroll
    for (int kc = 0; kc < 8; kc++) {
      const float* src = W + (size_t)(ga*256 + gr*16 + lm)*256 + kc*32 + lq*8;
      v8s f;
      #pragma unroll
      for (int j = 0; j < 8; j++) f[j] = (short)f2bf(src[j]);
      wfr[ti][kc] = f;
    }
  }
  __syncthreads();

  bool act = (lq < 2);
  int lql = lq & 1;                       // clamped for inactive lanes (valid addr)
  int lo = (lql*16 + lm)*16;
  size_t off0 = (size_t)bg*8192 + (size_t)(2*w)*512 + lo;
  size_t off1 = (size_t)bg*8192 + (size_t)(2*w + 1)*512 + lo;
  int u0 = 2*w*16 + lm, u1 = (2*w + 1)*16 + lm;

  us4 gA[4], gB[4];
  {
    int t0 = dir ? 511 : 0;
    const ushort_t* p = gx2 + (size_t)(dir*512 + t0)*65536;
    #pragma unroll
    for (int ga = 0; ga < 4; ga++) {
      gA[ga] = *(const us4*)(p + off0 + ga*4);
      gB[ga] = *(const us4*)(p + off1 + ga*4);
    }
  }

  for (int n = 0; n < 512; ++n) {
    int t = dir ? (511 - n) : n;
    const ushort_t* hrd = (const ushort_t*)hsh[n & 1];
    v4f acc[8];
    #pragma unroll
    for (int i = 0; i < 8; i++) acc[i] = (v4f)0.f;
    #pragma unroll
    for (int kc = 0; kc < 8; kc++) {
      v8s A = *(const v8s*)(hrd + lm*PITCH_H + kc*32 + lq*8);
      acc[0] = __builtin_amdgcn_mfma_f32_16x16x32_bf16(A, wfr[0][kc], acc[0], 0, 0, 0);
      acc[1] = __builtin_amdgcn_mfma_f32_16x16x32_bf16(A, wfr[1][kc], acc[1], 0, 0, 0);
      acc[2] = __builtin_amdgcn_mfma_f32_16x16x32_bf16(A, wfr[2][kc], acc[2], 0, 0, 0);
      acc[3] = __builtin_amdgcn_mfma_f32_16x16x32_bf16(A, wfr[3][kc], acc[3], 0, 0, 0);
      acc[4] = __builtin_amdgcn_mfma_f32_16x16x32_bf16(A, wfr[4][kc], acc[4], 0, 0, 0);
      acc[5] = __builtin_amdgcn_mfma_f32_16x16x32_bf16(A, wfr[5][kc], acc[5], 0, 0, 0);
      v8s B0 = *(const v8s*)(Wl + ((size_t)((2*w + 0)*8 + kc)*64 + l)*8);
      acc[6] = __builtin_amdgcn_mfma_f32_16x16x32_bf16(A, B0, acc[6], 0, 0, 0);
      v8s B1 = *(const v8s*)(Wl + ((size_t)((2*w + 1)*8 + kc)*64 + l)*8);
      acc[7] = __builtin_amdgcn_mfma_f32_16x16x32_bf16(A, B1, acc[7], 0, 0, 0);
    }
    int nn = (n < 511) ? (n + 1) : 511;
    int t2 = dir ? (511 - nn) : nn;
    const ushort_t* pnext = gx2 + (size_t)(dir*512 + t2)*65536;
    ushort_t* hwr = (ushort_t*)hsh[(n + 1) & 1];
    size_t hsb = ((size_t)(dir*512 + t)*64 + bg*8)*256;
    // ---- epilogue group 0 (units u0) ----
    if (act) {
      #pragma unroll
      for (int r = 0; r < 4; r++) {
        float pi = acc[0][r] + bf2f(gA[0][r]);
        float pf = acc[1][r] + bf2f(gA[1][r]);
        float pg = acc[2][r] + bf2f(gA[2][r]);
        float po = acc[3][r] + bf2f(gA[3][r]);
        float ii = sigm(pi), ff = sigm(pf), gg = tanhp(pg), oo = sigm(po);
        int b = lq*4 + r;
        float c0 = csh[b][u0];
        float cn = ff*c0 + ii*gg;
        csh[b][u0] = cn;
        ushort_t hb = f2bf(oo * tanhp(cn));
        hwr[b*PITCH_H + u0] = hb;
        hs[hsb + (size_t)b*256 + u0] = hb;
      }
    }
    #pragma unroll
    for (int ga = 0; ga < 4; ga++) gA[ga] = *(const us4*)(pnext + off0 + ga*4);
    // ---- epilogue group 1 (units u1) ----
    if (act) {
      #pragma unroll
      for (int r = 0; r < 4; r++) {
        float pi = acc[4][r] + bf2f(gB[0][r]);
        float pf = acc[5][r] + bf2f(gB[1][r]);
        float pg = acc[6][r] + bf2f(gB[2][r]);
        float po = acc[7][r] + bf2f(gB[3][r]);
        float ii = sigm(pi), ff = sigm(pf), gg = tanhp(pg), oo = sigm(po);
        int b = lq*4 + r;
        float c0 = csh[b][u1];
        float cn = ff*c0 + ii*gg;
        csh[b][u1] = cn;
        ushort_t hb = f2bf(oo * tanhp(cn));
        hwr[b*PITCH_H + u1] = hb;
        hs[hsb + (size_t)b*256 + u1] = hb;
      }
    }
    #pragma unroll
    for (int ga = 0; ga < 4; ga++) gB[ga] = *(const us4*)(pnext + off1 + ga*4);
    block_sync_lds();   // lgkmcnt-only barrier: gx prefetch stays in flight
  }
}

// ---------------- K4: emissions[b][s][17] = [h_f, h_b] @ cls_w^T + cls_b (fp32) ----------------
__global__ __launch_bounds__(256) void k_emis(
    const ushort_t* __restrict__ hs, const float* __restrict__ clsw,
    const float* __restrict__ clsb, float* __restrict__ emis)
{
  int tid = threadIdx.x;
  if (tid >= 255) return;
  int wi = blockIdx.x * 15 + tid / 17;
  int tau = tid % 17;
  if (wi >= B_ * S_) return;
  int b = wi >> 9, s = wi & 511;
  const ushort_t* hf  = hs + ((size_t)s*64 + b) * 256;
  const ushort_t* hbk = hs + (((size_t)512 + s)*64 + b) * 256;
  const float* cwf = clsw + (size_t)tau * 512;
  const float* cwb = cwf + 256;
  union { unsigned int u; float f; } bc;
  float acc = clsb[tau];
  for (int k = 0; k < 256; k += 4) {
    us4 h4 = *(const us4*)(hf + k); f4 w4 = *(const f4*)(cwf + k);
    #pragma unroll
    for (int j = 0; j < 4; j++) { bc.u = (unsigned int)h4[j] << 16; acc += bc.f * w4[j]; }
  }
  for (int k = 0; k < 256; k += 4) {
    us4 h4 = *(const us4*)(hbk + k); f4 w4 = *(const f4*)(cwb + k);
    #pragma unroll
    for (int j = 0; j < 4; j++) { bc.u = (unsigned int)h4[j] << 16; acc += bc.f * w4[j]; }
  }
  emis[(size_t)wi * 17 + tau] = acc;
}

// ---------------- K5: CRF — 64 blocks (one per batch): wave0 = loss fwd, wave1 = viterbi --------
__global__ __launch_bounds__(128) void k_crf(
    const float* __restrict__ emis, const int* __restrict__ labels,
    const int* __restrict__ mask, const float* __restrict__ startt,
    const float* __restrict__ endt, const float* __restrict__ trans,
    float* __restrict__ lossp, float* __restrict__ outp)
{
  __shared__ unsigned char bps[511][17];
  int b = blockIdx.x;
  int tid = threadIdx.x, wv = tid >> 6, l = tid & 63;
  int tauc = (l < 17) ? l : 0;
  float tc[17];
  #pragma unroll
  for (int i = 0; i < 17; i++) tc[i] = trans[i*17 + tauc];
  const float* eb = emis + (size_t)b * 512 * 17;
  float alpha = startt[tauc] + eb[tauc];
  if (l >= 17) alpha = -3e30f;

  if (wv == 0) {
    for (int t = 1; t < 512; t++) {
      float e = (l < 17) ? eb[t*17 + l] : 0.f;
      int mt = mask[b*512 + t];
      float arr[17]; float mx = -3e30f;
      #pragma unroll
      for (int i = 0; i < 17; i++) {
        float av = __shfl(alpha, i);
        arr[i] = av + tc[i];
        mx = fmaxf(mx, arr[i]);
      }
      float ss = 0.f;
      #pragma unroll
      for (int i = 0; i < 17; i++) ss += expf(arr[i] - mx);
      float nxt = mx + logf(ss) + e;
      if (mt > 0 && l < 17) alpha = nxt;
    }
    float a2 = (l < 17) ? (alpha + endt[l]) : -3e30f;
    float mx = a2;
    #pragma unroll
    for (int o = 32; o > 0; o >>= 1) mx = fmaxf(mx, __shfl_xor(mx, o));
    float ss = (l < 17) ? expf(a2 - mx) : 0.f;
    #pragma unroll
    for (int o = 32; o > 0; o >>= 1) ss += __shfl_xor(ss, o);
    float denom = mx + logf(ss);
    float ns = 0.f; int msum = 0;
    for (int t = l; t < 512; t += 64) {
      int tg = labels[b*512 + t];
      int mt = mask[b*512 + t];
      msum += (mt > 0);
      if (mt > 0) {
        ns += eb[t*17 + tg];
        if (t > 0) ns += trans[labels[b*512 + t - 1]*17 + tg];
      }
    }
    #pragma unroll
    for (int o = 32; o > 0; o >>= 1) { ns += __shfl_xor(ns, o); msum += __shfl_xor(msum, o); }
    if (l == 0) {
      int lidx = msum - 1;
      float num = ns + startt[labels[b*512]] + endt[labels[b*512 + lidx]];
      lossp[b] = num - denom;
    }
  } else {
    for (int t = 1; t < 512; t++) {
      float e = (l < 17) ? eb[t*17 + l] : 0.f;
      int mt = mask[b*512 + t];
      float best = -3e30f; int bi = 0;
      #pragma unroll
      for (int i = 0; i < 17; i++) {
        float v = __shfl(alpha, i) + tc[i];
        if (v > best) { best = v; bi = i; }   // first-max tie-break = np.argmax
      }
      float nxt = best + e;
      int bpv = (mt > 0) ? bi : l;
      if (l < 17) {
        bps[t-1][l] = (unsigned char)bpv;
        if (mt > 0) alpha = nxt;
      }
    }
    float a2 = (l < 17) ? (alpha + endt[l]) : -3e30f;
    float av[17];
    #pragma unroll
    for (int i = 0; i < 17; i++) av[i] = __shfl(a2, i);
    int bt = 0; float bv2 = av[0];
    #pragma unroll
    for (int i = 1; i < 17; i++) if (av[i] > bv2) { bv2 = av[i]; bt = i; }
    if (l == 0) outp[1 + b*512 + 511] = (float)bt;
    int tg = bt;
    for (int t = 510; t >= 0; --t) {
      tg = bps[t][tg];
      if (l == 0) outp[1 + b*512 + t] = (float)tg;
    }
  }
}

// ---------------- K6: loss = -mean(num - denom), fp32 ----------------
__global__ __launch_bounds__(64) void k_final(const float* __restrict__ lossp,
                                              float* __restrict__ outp)
{
  int l = threadIdx.x;
  float v = lossp[l];
  #pragma unroll
  for (int o = 32; o > 0; o >>= 1) v += __shfl_xor(v, o);
  if (l == 0) outp[0] = -(v / 64.f);
}

// ---------------- host ----------------
extern "C" void kernel_launch(void* const* d_in, const int* in_sizes, int n_in,
                              void* d_out, int out_size, void* d_ws, size_t ws_size,
                              hipStream_t stream)
{
  (void)in_sizes; (void)n_in; (void)out_size; (void)ws_size;
  const int*   tok   = (const int*)d_in[0];
  const int*   ctok  = (const int*)d_in[1];
  const int*   labels= (const int*)d_in[2];
  const int*   amask = (const int*)d_in[3];
  const float* wemb  = (const float*)d_in[4];
  const float* cemb  = (const float*)d_in[5];
  const float* convw = (const float*)d_in[6];
  const float* convb = (const float*)d_in[7];
  const float* wihf  = (const float*)d_in[8];
  const float* whhf  = (const float*)d_in[9];
  const float* bfv   = (const float*)d_in[10];
  const float* wihb  = (const float*)d_in[11];
  const float* whhb  = (const float*)d_in[12];
  const float* bbv   = (const float*)d_in[13];
  const float* clsw  = (const float*)d_in[14];
  const float* clsb  = (const float*)d_in[15];
  const float* stt   = (const float*)d_in[16];
  const float* ent   = (const float*)d_in[17];
  const float* trn   = (const float*)d_in[18];

  // workspace layout (bytes): [z 20,971,520][gx2 134,217,728][hs 33,554,432]
  //                           [emis 2,228,224][lossp 256]  = 190,972,160
  char* ws = (char*)d_ws;
  ushort_t* z    = (ushort_t*)(ws);
  ushort_t* gx2  = (ushort_t*)(ws + 20971520);
  ushort_t* hs   = (ushort_t*)(ws + 155189248);
  float*    emis = (float*)(ws + 188743680);
  float*    lossp= (float*)(ws + 190971904);

  hipLaunchKernelGGL(k_embed,   dim3(B_*S_),       dim3(64),  0, stream,
                     tok, ctok, wemb, cemb, convw, convb, z);
  hipLaunchKernelGGL(k_gemm_gx, dim3(256, 32),     dim3(256), 0, stream,
                     z, wihf, wihb, bfv, bbv, gx2);
  hipLaunchKernelGGL(k_lstm,    dim3(16),          dim3(512), 0, stream,
                     gx2, whhf, whhb, hs);
  hipLaunchKernelGGL(k_emis,    dim3((B_*S_ + 14)/15), dim3(256), 0, stream,
                     hs, clsw, clsb, emis);
  hipLaunchKernelGGL(k_crf,     dim3(64),          dim3(128), 0, stream,
                     emis, labels, amask, stt, ent, trn, lossp, (float*)d_out);
  hipLaunchKernelGGL(k_final,   dim3(1),           dim3(64),  0, stream,
                     lossp, (float*)d_out);
}

// Round 7
// 3737.110 us; speedup vs baseline: 2.7398x; 1.0860x over previous
//
#include <hip/hip_runtime.h>

// ---------------- problem constants ----------------
#define B_  64
#define S_  512
#define L_  16
#define WD_ 200
#define CD_ 30
#define FN_ 4
#define KW_ 3
#define H_  256
#define T_  17
#define D_  320   // WD + CD*FN
#define PITCH 280  // h-row pitch in ushorts: 140 dwords == 12 mod 32 -> conflict-free b128

typedef unsigned short ushort_t;
typedef __attribute__((ext_vector_type(8))) short v8s;   // bf16x8 MFMA frag
typedef __attribute__((ext_vector_type(4))) float v4f;   // fp32x4 MFMA acc
typedef __attribute__((ext_vector_type(4))) float f4;
typedef __attribute__((ext_vector_type(4))) unsigned int ui4;
typedef __attribute__((ext_vector_type(4))) unsigned short us4;

__device__ __forceinline__ float bf2f(unsigned short u) {
  union { unsigned int i; float f; } v; v.i = ((unsigned int)u) << 16; return v.f;
}
__device__ __forceinline__ unsigned short f2bf(float f) {
  union { float f; unsigned int i; } v; v.f = f;
  unsigned int r = v.i + 0x7fffu + ((v.i >> 16) & 1u);   // RNE
  return (unsigned short)(r >> 16);
}
__device__ __forceinline__ float sigm(float x) {
  return __fdividef(1.f, 1.f + __expf(-x));
}
__device__ __forceinline__ float tanhp(float x) {
  float e = __expf(2.f * x);
  return __fdividef(e - 1.f, e + 1.f);
}
// barrier that does NOT drain vmcnt (keeps global prefetch loads in flight)
__device__ __forceinline__ void block_sync_lds() {
  __asm__ volatile("s_waitcnt lgkmcnt(0)\n\ts_barrier" ::: "memory");
}

// ---------------- K1: word emb (f32->bf16) + char CNN + maxpool -> z [(s,b)-major, 320] ---------
__global__ __launch_bounds__(64) void k_embed(
    const int* __restrict__ tok, const int* __restrict__ ctok,
    const float* __restrict__ wemb, const float* __restrict__ cemb,
    const float* __restrict__ cw, const float* __restrict__ cb,
    ushort_t* __restrict__ z)
{
  int w = blockIdx.x;                 // input word index = b*S + s
  int b = w >> 9, s = w & 511;
  size_t ro = (size_t)s * 64 + b;     // OUTPUT row: (s,b)-major
  int l = threadIdx.x;
  __shared__ float ce[L_][32];
  if (l < L_) {
    int cid = ctok[w * L_ + l];
    const float* row = cemb + (size_t)cid * CD_;
    #pragma unroll
    for (int j = 0; j < CD_; ++j) ce[l][j] = row[j];
  }
  int t = tok[w];
  const f4* src = (const f4*)(wemb + (size_t)t * WD_);
  if (l < 50) {
    f4 v = src[l];
    us4 o; o[0]=f2bf(v[0]); o[1]=f2bf(v[1]); o[2]=f2bf(v[2]); o[3]=f2bf(v[3]);
    *(us4*)(z + ro * D_ + l*4) = o;
  }
  __syncthreads();
  for (int oc = l; oc < CD_ * FN_; oc += 64) {
    int c = oc >> 2;
    float w0 = cw[oc*3+0], w1 = cw[oc*3+1], w2 = cw[oc*3+2];
    float mx = -3e30f;
    #pragma unroll
    for (int p = 0; p < L_ - KW_ + 1; ++p) {
      float sv = ce[p][c]*w0 + ce[p+1][c]*w1 + ce[p+2][c]*w2;
      mx = fmaxf(mx, sv);
    }
    z[ro * D_ + WD_ + oc] = f2bf(mx + cb[oc]);
  }
}

// ---------------- K2: gx2 = z @ W_ih^T + b, packed for k_lstm lane-slots (us4 stores) -----------
// gx2 idx = ((dir*512+s)*4+bg)*16384 + (((w2*2+j)*4+gate)*16+lm2)*16 + b_local (bf16)
__global__ __launch_bounds__(256) void k_gemm_gx(
    const ushort_t* __restrict__ z, const float* __restrict__ wf,
    const float* __restrict__ wb, const float* __restrict__ bfv,
    const float* __restrict__ bbv, ushort_t* __restrict__ gx2)
{
  __shared__ ushort_t As[128 * 40];
  __shared__ ushort_t Bs[64 * 40];
  int m0 = blockIdx.x * 128;          // m = s*64 + b (z is (s,b)-major)
  int n0g = blockIdx.y * 64;
  int dir = n0g >> 10;
  int ncol0 = n0g & 1023;
  const float* W = dir ? wb : wf;
  const float* bias = dir ? bbv : bfv;
  int tid = threadIdx.x;
  int wv = tid >> 6, l = tid & 63;
  int lm = l & 15, lq = l >> 4;
  v4f acc[2][4];
  #pragma unroll
  for (int i = 0; i < 2; i++)
    #pragma unroll
    for (int j = 0; j < 4; j++) acc[i][j] = (v4f)0.f;

  for (int kc = 0; kc < 10; ++kc) {
    int k0 = kc * 32;
    #pragma unroll
    for (int rep = 0; rep < 2; ++rep) {
      int idx = rep * 256 + tid;
      int row = idx >> 2, q = idx & 3;
      *(ui4*)(As + row*40 + q*8) =
          *(const ui4*)(z + (size_t)(m0 + row)*D_ + k0 + q*8);
    }
    {
      int row = tid >> 2, q = tid & 3;
      const float* src = W + (size_t)(ncol0 + row)*D_ + k0 + q*8;
      f4 a = *(const f4*)src, b2 = *(const f4*)(src + 4);
      us4 o0, o1;
      o0[0]=f2bf(a[0]); o0[1]=f2bf(a[1]); o0[2]=f2bf(a[2]); o0[3]=f2bf(a[3]);
      o1[0]=f2bf(b2[0]); o1[1]=f2bf(b2[1]); o1[2]=f2bf(b2[2]); o1[3]=f2bf(b2[3]);
      *(us4*)(Bs + row*40 + q*8) = o0;
      *(us4*)(Bs + row*40 + q*8 + 4) = o1;
    }
    __syncthreads();
    v8s a0 = *(const v8s*)(As + (wv*32 + lm)*40 + lq*8);
    v8s a1 = *(const v8s*)(As + (wv*32 + 16 + lm)*40 + lq*8);
    #pragma unroll
    for (int nt = 0; nt < 4; ++nt) {
      v8s b = *(const v8s*)(Bs + (nt*16 + lm)*40 + lq*8);
      acc[0][nt] = __builtin_amdgcn_mfma_f32_16x16x32_bf16(a0, b, acc[0][nt], 0, 0, 0);
      acc[1][nt] = __builtin_amdgcn_mfma_f32_16x16x32_bf16(a1, b, acc[1][nt], 0, 0, 0);
    }
    __syncthreads();
  }
  // epilogue: r spans 4 consecutive batches -> one aligned us4 store each
  float bval[4];
  #pragma unroll
  for (int nt = 0; nt < 4; nt++) bval[nt] = bias[ncol0 + nt*16 + lm];
  #pragma unroll
  for (int mt = 0; mt < 2; mt++)
    #pragma unroll
    for (int nt = 0; nt < 4; nt++) {
      int m = m0 + wv*32 + mt*16 + lq*4;   // + r
      int b = m & 63, s = m >> 6;
      int col = ncol0 + nt*16 + lm;
      int gate = col >> 8, unit = col & 255;
      int w2 = unit >> 5, j = (unit >> 4) & 1, lm2 = unit & 15;
      int bg = b >> 4, bl = b & 15;        // bl multiple of 4
      us4 o;
      #pragma unroll
      for (int r = 0; r < 4; r++) o[r] = f2bf(acc[mt][nt][r] + bval[nt]);
      size_t idx = ((size_t)(dir*512 + s)*4 + bg)*16384
                 + (size_t)(((w2*2 + j)*4 + gate)*16 + lm2)*16 + bl;
      *(us4*)(gx2 + idx) = o;
    }
}

// ---------------- K3: intra-CU persistent LSTM v3 -----------------------------------------------
// 8 blocks: dir(2) x bg(4, B=16). 8 waves; wave w owns units [32w,32w+32) x 4 gates
// = 8 MFMA tiles: 6 in registers, 2 (gates g,o of upper 16 units) in LDS. c in registers.
__global__ __launch_bounds__(512, 2) void k_lstm(
    const ushort_t* __restrict__ gx2,
    const float* __restrict__ whhf, const float* __restrict__ whhb,
    ushort_t* __restrict__ hs)
{
  __shared__ ushort_t Wl[16 * 8 * 512];       // 128 KB
  __shared__ ushort_t hsh[2][16][PITCH];      // 17.5 KB
  int bid = blockIdx.x;
  int dir = bid >> 2, bg = bid & 3;
  int tid = threadIdx.x, w = tid >> 6, l = tid & 63;
  int lm = l & 15, lq = l >> 4;
  const float* W = dir ? whhb : whhf;

  for (int i = tid; i < 2 * 16 * PITCH; i += 512) ((ushort_t*)hsh)[i] = 0;
  // LDS W tiles: tile t=(w2,gsel): gate=2+gsel, rows gate*256 + w2*32 + 16 + lm2
  for (int idx = tid; idx < 16 * 8 * 64; idx += 512) {
    int t = idx >> 9, kc = (idx >> 6) & 7, ln = idx & 63;
    int lq2 = ln >> 4, lm2 = ln & 15;
    int w2 = t >> 1, gsel = t & 1;
    int row = (2 + gsel)*256 + w2*32 + 16 + lm2;
    const float* src = W + (size_t)row*256 + kc*32 + lq2*8;
    v8s f;
    #pragma unroll
    for (int jj = 0; jj < 8; jj++) f[jj] = (short)f2bf(src[jj]);
    *(v8s*)(Wl + ((size_t)(t*8 + kc)*64 + ln)*8) = f;
  }
  // register W tiles: ti 0..3 = gates i,f,g,o (lower 16 units); ti 4,5 = gates i,f (upper 16)
  v8s wfr[6][8];
  #pragma unroll
  for (int ti = 0; ti < 6; ti++) {
    int gate = (ti < 4) ? ti : (ti - 4);
    int jr = (ti < 4) ? 0 : 16;
    #pragma unroll
    for (int kc = 0; kc < 8; kc++) {
      const float* src = W + (size_t)(gate*256 + w*32 + jr + lm)*256 + kc*32 + lq*8;
      v8s f;
      #pragma unroll
      for (int jj = 0; jj < 8; jj++) f[jj] = (short)f2bf(src[jj]);
      wfr[ti][kc] = f;
    }
  }
  __syncthreads();

  float c0[4] = {0.f,0.f,0.f,0.f}, c1[4] = {0.f,0.f,0.f,0.f};
  int u0 = w*32 + lm, u1 = w*32 + 16 + lm;
  // gx lane offsets: k = j*4 + gate
  int goff[8];
  #pragma unroll
  for (int j = 0; j < 2; j++)
    #pragma unroll
    for (int ga = 0; ga < 4; ga++)
      goff[j*4 + ga] = (((w*2 + j)*4 + ga)*16 + lm)*16 + lq*4;

  us4 g0[8];
  {
    int t0 = dir ? 511 : 0;
    const ushort_t* gb = gx2 + ((size_t)(dir*512 + t0)*4 + bg)*16384;
    #pragma unroll
    for (int k = 0; k < 8; k++) g0[k] = *(const us4*)(gb + goff[k]);
  }

  for (int n = 0; n < 512; ++n) {
    int t = dir ? (511 - n) : n;
    const ushort_t* hrd = (const ushort_t*)hsh + (size_t)(n & 1)*16*PITCH;
    v4f acc[8];
    #pragma unroll
    for (int i = 0; i < 8; i++) acc[i] = (v4f)0.f;
    v8s A0 = *(const v8s*)(hrd + lm*PITCH + lq*8);
    #pragma unroll
    for (int kc = 0; kc < 8; kc++) {
      v8s An = (kc < 7) ? *(const v8s*)(hrd + lm*PITCH + (kc+1)*32 + lq*8) : A0;
      acc[0] = __builtin_amdgcn_mfma_f32_16x16x32_bf16(A0, wfr[0][kc], acc[0], 0, 0, 0);
      acc[1] = __builtin_amdgcn_mfma_f32_16x16x32_bf16(A0, wfr[1][kc], acc[1], 0, 0, 0);
      acc[2] = __builtin_amdgcn_mfma_f32_16x16x32_bf16(A0, wfr[2][kc], acc[2], 0, 0, 0);
      acc[3] = __builtin_amdgcn_mfma_f32_16x16x32_bf16(A0, wfr[3][kc], acc[3], 0, 0, 0);
      acc[4] = __builtin_amdgcn_mfma_f32_16x16x32_bf16(A0, wfr[4][kc], acc[4], 0, 0, 0);
      acc[5] = __builtin_amdgcn_mfma_f32_16x16x32_bf16(A0, wfr[5][kc], acc[5], 0, 0, 0);
      v8s B6 = *(const v8s*)(Wl + ((size_t)((w*2 + 0)*8 + kc)*64 + l)*8);
      acc[6] = __builtin_amdgcn_mfma_f32_16x16x32_bf16(A0, B6, acc[6], 0, 0, 0);
      v8s B7 = *(const v8s*)(Wl + ((size_t)((w*2 + 1)*8 + kc)*64 + l)*8);
      acc[7] = __builtin_amdgcn_mfma_f32_16x16x32_bf16(A0, B7, acc[7], 0, 0, 0);
      A0 = An;
    }
    // prefetch next step's gx (full MFMA block + epilogue before use)
    us4 g1[8];
    {
      int nn = (n < 511) ? (n + 1) : n;
      int t2 = dir ? (511 - nn) : nn;
      const ushort_t* gb = gx2 + ((size_t)(dir*512 + t2)*4 + bg)*16384;
      #pragma unroll
      for (int k = 0; k < 8; k++) g1[k] = *(const us4*)(gb + goff[k]);
    }
    ushort_t* hwr = (ushort_t*)hsh + (size_t)((n + 1) & 1)*16*PITCH;
    size_t hsb = ((size_t)(dir*512 + t)*64 + bg*16)*256;
    // ---- units u0 (lower 16): gates = acc[0..3] ----
    #pragma unroll
    for (int r = 0; r < 4; r++) {
      float pi = acc[0][r] + bf2f(g0[0][r]);
      float pf = acc[1][r] + bf2f(g0[1][r]);
      float pg = acc[2][r] + bf2f(g0[2][r]);
      float po = acc[3][r] + bf2f(g0[3][r]);
      float ii = sigm(pi), ff = sigm(pf), gg = tanhp(pg), oo = sigm(po);
      c0[r] = ff*c0[r] + ii*gg;
      ushort_t hb = f2bf(oo * tanhp(c0[r]));
      int b = lq*4 + r;
      hwr[b*PITCH + u0] = hb;
      hs[hsb + (size_t)b*256 + u0] = hb;
    }
    // ---- units u1 (upper 16): i=acc[4], f=acc[5], g=acc[6], o=acc[7] ----
    #pragma unroll
    for (int r = 0; r < 4; r++) {
      float pi = acc[4][r] + bf2f(g0[4][r]);
      float pf = acc[5][r] + bf2f(g0[5][r]);
      float pg = acc[6][r] + bf2f(g0[6][r]);
      float po = acc[7][r] + bf2f(g0[7][r]);
      float ii = sigm(pi), ff = sigm(pf), gg = tanhp(pg), oo = sigm(po);
      c1[r] = ff*c1[r] + ii*gg;
      ushort_t hb = f2bf(oo * tanhp(c1[r]));
      int b = lq*4 + r;
      hwr[b*PITCH + u1] = hb;
      hs[hsb + (size_t)b*256 + u1] = hb;
    }
    #pragma unroll
    for (int k = 0; k < 8; k++) g0[k] = g1[k];
    block_sync_lds();   // lgkmcnt-only barrier: gx prefetch stays in flight
  }
}

// ---------------- K4: emissions[b][s][17] = [h_f, h_b] @ cls_w^T + cls_b (fp32) ----------------
__global__ __launch_bounds__(256) void k_emis(
    const ushort_t* __restrict__ hs, const float* __restrict__ clsw,
    const float* __restrict__ clsb, float* __restrict__ emis)
{
  int tid = threadIdx.x;
  if (tid >= 255) return;
  int wi = blockIdx.x * 15 + tid / 17;
  int tau = tid % 17;
  if (wi >= B_ * S_) return;
  int b = wi >> 9, s = wi & 511;
  const ushort_t* hf  = hs + ((size_t)s*64 + b) * 256;
  const ushort_t* hbk = hs + (((size_t)512 + s)*64 + b) * 256;
  const float* cwf = clsw + (size_t)tau * 512;
  const float* cwb = cwf + 256;
  union { unsigned int u; float f; } bc;
  float acc = clsb[tau];
  for (int k = 0; k < 256; k += 4) {
    us4 h4 = *(const us4*)(hf + k); f4 w4 = *(const f4*)(cwf + k);
    #pragma unroll
    for (int j = 0; j < 4; j++) { bc.u = (unsigned int)h4[j] << 16; acc += bc.f * w4[j]; }
  }
  for (int k = 0; k < 256; k += 4) {
    us4 h4 = *(const us4*)(hbk + k); f4 w4 = *(const f4*)(cwb + k);
    #pragma unroll
    for (int j = 0; j < 4; j++) { bc.u = (unsigned int)h4[j] << 16; acc += bc.f * w4[j]; }
  }
  emis[(size_t)wi * 17 + tau] = acc;
}

// ---------------- K5: CRF — 64 blocks (one per batch): wave0 = loss fwd, wave1 = viterbi --------
__global__ __launch_bounds__(128) void k_crf(
    const float* __restrict__ emis, const int* __restrict__ labels,
    const int* __restrict__ mask, const float* __restrict__ startt,
    const float* __restrict__ endt, const float* __restrict__ trans,
    float* __restrict__ lossp, float* __restrict__ outp)
{
  __shared__ unsigned char bps[511][17];
  int b = blockIdx.x;
  int tid = threadIdx.x, wv = tid >> 6, l = tid & 63;
  int tauc = (l < 17) ? l : 0;
  float tc[17];
  #pragma unroll
  for (int i = 0; i < 17; i++) tc[i] = trans[i*17 + tauc];
  const float* eb = emis + (size_t)b * 512 * 17;
  float alpha = startt[tauc] + eb[tauc];
  if (l >= 17) alpha = -3e30f;

  if (wv == 0) {
    for (int t = 1; t < 512; t++) {
      float e = (l < 17) ? eb[t*17 + l] : 0.f;
      int mt = mask[b*512 + t];
      float arr[17]; float mx = -3e30f;
      #pragma unroll
      for (int i = 0; i < 17; i++) {
        float av = __shfl(alpha, i);
        arr[i] = av + tc[i];
        mx = fmaxf(mx, arr[i]);
      }
      float ss = 0.f;
      #pragma unroll
      for (int i = 0; i < 17; i++) ss += expf(arr[i] - mx);
      float nxt = mx + logf(ss) + e;
      if (mt > 0 && l < 17) alpha = nxt;
    }
    float a2 = (l < 17) ? (alpha + endt[l]) : -3e30f;
    float mx = a2;
    #pragma unroll
    for (int o = 32; o > 0; o >>= 1) mx = fmaxf(mx, __shfl_xor(mx, o));
    float ss = (l < 17) ? expf(a2 - mx) : 0.f;
    #pragma unroll
    for (int o = 32; o > 0; o >>= 1) ss += __shfl_xor(ss, o);
    float denom = mx + logf(ss);
    float ns = 0.f; int msum = 0;
    for (int t = l; t < 512; t += 64) {
      int tg = labels[b*512 + t];
      int mt = mask[b*512 + t];
      msum += (mt > 0);
      if (mt > 0) {
        ns += eb[t*17 + tg];
        if (t > 0) ns += trans[labels[b*512 + t - 1]*17 + tg];
      }
    }
    #pragma unroll
    for (int o = 32; o > 0; o >>= 1) { ns += __shfl_xor(ns, o); msum += __shfl_xor(msum, o); }
    if (l == 0) {
      int lidx = msum - 1;
      float num = ns + startt[labels[b*512]] + endt[labels[b*512 + lidx]];
      lossp[b] = num - denom;
    }
  } else {
    for (int t = 1; t < 512; t++) {
      float e = (l < 17) ? eb[t*17 + l] : 0.f;
      int mt = mask[b*512 + t];
      float best = -3e30f; int bi = 0;
      #pragma unroll
      for (int i = 0; i < 17; i++) {
        float v = __shfl(alpha, i) + tc[i];
        if (v > best) { best = v; bi = i; }   // first-max tie-break = np.argmax
      }
      float nxt = best + e;
      int bpv = (mt > 0) ? bi : l;
      if (l < 17) {
        bps[t-1][l] = (unsigned char)bpv;
        if (mt > 0) alpha = nxt;
      }
    }
    float a2 = (l < 17) ? (alpha + endt[l]) : -3e30f;
    float av[17];
    #pragma unroll
    for (int i = 0; i < 17; i++) av[i] = __shfl(a2, i);
    int bt = 0; float bv2 = av[0];
    #pragma unroll
    for (int i = 1; i < 17; i++) if (av[i] > bv2) { bv2 = av[i]; bt = i; }
    if (l == 0) outp[1 + b*512 + 511] = (float)bt;
    int tg = bt;
    for (int t = 510; t >= 0; --t) {
      tg = bps[t][tg];
      if (l == 0) outp[1 + b*512 + t] = (float)tg;
    }
  }
}

// ---------------- K6: loss = -mean(num - denom), fp32 ----------------
__global__ __launch_bounds__(64) void k_final(const float* __restrict__ lossp,
                                              float* __restrict__ outp)
{
  int l = threadIdx.x;
  float v = lossp[l];
  #pragma unroll
  for (int o = 32; o > 0; o >>= 1) v += __shfl_xor(v, o);
  if (l == 0) outp[0] = -(v / 64.f);
}

// ---------------- host ----------------
extern "C" void kernel_launch(void* const* d_in, const int* in_sizes, int n_in,
                              void* d_out, int out_size, void* d_ws, size_t ws_size,
                              hipStream_t stream)
{
  (void)in_sizes; (void)n_in; (void)out_size; (void)ws_size;
  const int*   tok   = (const int*)d_in[0];
  const int*   ctok  = (const int*)d_in[1];
  const int*   labels= (const int*)d_in[2];
  const int*   amask = (const int*)d_in[3];
  const float* wemb  = (const float*)d_in[4];
  const float* cemb  = (const float*)d_in[5];
  const float* convw = (const float*)d_in[6];
  const float* convb = (const float*)d_in[7];
  const float* wihf  = (const float*)d_in[8];
  const float* whhf  = (const float*)d_in[9];
  const float* bfv   = (const float*)d_in[10];
  const float* wihb  = (const float*)d_in[11];
  const float* whhb  = (const float*)d_in[12];
  const float* bbv   = (const float*)d_in[13];
  const float* clsw  = (const float*)d_in[14];
  const float* clsb  = (const float*)d_in[15];
  const float* stt   = (const float*)d_in[16];
  const float* ent   = (const float*)d_in[17];
  const float* trn   = (const float*)d_in[18];

  // workspace layout (bytes): [z 20,971,520][gx2 134,217,728][hs 33,554,432]
  //                           [emis 2,228,224][lossp 256]
  char* ws = (char*)d_ws;
  ushort_t* z    = (ushort_t*)(ws);
  ushort_t* gx2  = (ushort_t*)(ws + 20971520);
  ushort_t* hs   = (ushort_t*)(ws + 155189248);
  float*    emis = (float*)(ws + 188743680);
  float*    lossp= (float*)(ws + 190971904);

  hipLaunchKernelGGL(k_embed,   dim3(B_*S_),       dim3(64),  0, stream,
                     tok, ctok, wemb, cemb, convw, convb, z);
  hipLaunchKernelGGL(k_gemm_gx, dim3(256, 32),     dim3(256), 0, stream,
                     z, wihf, wihb, bfv, bbv, gx2);
  hipLaunchKernelGGL(k_lstm,    dim3(8),           dim3(512), 0, stream,
                     gx2, whhf, whhb, hs);
  hipLaunchKernelGGL(k_emis,    dim3((B_*S_ + 14)/15), dim3(256), 0, stream,
                     hs, clsw, clsb, emis);
  hipLaunchKernelGGL(k_crf,     dim3(64),          dim3(128), 0, stream,
                     emis, labels, amask, stt, ent, trn, lossp, (float*)d_out);
  hipLaunchKernelGGL(k_final,   dim3(1),           dim3(64),  0, stream,
                     lossp, (float*)d_out);
}

// Round 8
// 2747.838 us; speedup vs baseline: 3.7262x; 1.3600x over previous
//
#include <hip/hip_runtime.h>

// ---------------- problem constants ----------------
#define B_  64
#define S_  512
#define L_  16
#define WD_ 200
#define CD_ 30
#define FN_ 4
#define KW_ 3
#define H_  256
#define T_  17
#define D_  320   // WD + CD*FN
#define PITCH 280  // h-row pitch in ushorts: 140 dwords == 12 mod 32 -> conflict-free b128

typedef unsigned short ushort_t;
typedef __attribute__((ext_vector_type(8))) short v8s;   // bf16x8 MFMA frag
typedef __attribute__((ext_vector_type(4))) float v4f;   // fp32x4 MFMA acc
typedef __attribute__((ext_vector_type(4))) float f4;
typedef __attribute__((ext_vector_type(4))) unsigned int ui4;
typedef __attribute__((ext_vector_type(4))) unsigned short us4;

__device__ __forceinline__ float bf2f(unsigned short u) {
  union { unsigned int i; float f; } v; v.i = ((unsigned int)u) << 16; return v.f;
}
__device__ __forceinline__ unsigned short f2bf(float f) {
  union { float f; unsigned int i; } v; v.f = f;
  unsigned int r = v.i + 0x7fffu + ((v.i >> 16) & 1u);   // RNE
  return (unsigned short)(r >> 16);
}
__device__ __forceinline__ float sigm(float x) {
  return __fdividef(1.f, 1.f + __expf(-x));
}
__device__ __forceinline__ float tanhp(float x) {
  float e = __expf(2.f * x);
  return __fdividef(e - 1.f, e + 1.f);
}
// barrier that does NOT drain vmcnt (keeps global prefetch loads in flight)
__device__ __forceinline__ void block_sync_lds() {
  __asm__ volatile("s_waitcnt lgkmcnt(0)\n\ts_barrier" ::: "memory");
}

// ---------------- K1: word emb (f32->bf16) + char CNN + maxpool -> z [(s,b)-major, 320] ---------
__global__ __launch_bounds__(64) void k_embed(
    const int* __restrict__ tok, const int* __restrict__ ctok,
    const float* __restrict__ wemb, const float* __restrict__ cemb,
    const float* __restrict__ cw, const float* __restrict__ cb,
    ushort_t* __restrict__ z)
{
  int w = blockIdx.x;                 // input word index = b*S + s
  int b = w >> 9, s = w & 511;
  size_t ro = (size_t)s * 64 + b;     // OUTPUT row: (s,b)-major
  int l = threadIdx.x;
  __shared__ float ce[L_][32];
  if (l < L_) {
    int cid = ctok[w * L_ + l];
    const float* row = cemb + (size_t)cid * CD_;
    #pragma unroll
    for (int j = 0; j < CD_; ++j) ce[l][j] = row[j];
  }
  int t = tok[w];
  const f4* src = (const f4*)(wemb + (size_t)t * WD_);
  if (l < 50) {
    f4 v = src[l];
    us4 o; o[0]=f2bf(v[0]); o[1]=f2bf(v[1]); o[2]=f2bf(v[2]); o[3]=f2bf(v[3]);
    *(us4*)(z + ro * D_ + l*4) = o;
  }
  __syncthreads();
  for (int oc = l; oc < CD_ * FN_; oc += 64) {
    int c = oc >> 2;
    float w0 = cw[oc*3+0], w1 = cw[oc*3+1], w2 = cw[oc*3+2];
    float mx = -3e30f;
    #pragma unroll
    for (int p = 0; p < L_ - KW_ + 1; ++p) {
      float sv = ce[p][c]*w0 + ce[p+1][c]*w1 + ce[p+2][c]*w2;
      mx = fmaxf(mx, sv);
    }
    z[ro * D_ + WD_ + oc] = f2bf(mx + cb[oc]);
  }
}

// ---------------- K2: gx2 = z @ W_ih^T + b, packed for k_lstm lane-slots (us4 stores) -----------
// gx2 idx = ((dir*512+s)*4+bg)*16384 + (((w2*2+j)*4+gate)*16+lm2)*16 + b_local (bf16)
__global__ __launch_bounds__(256) void k_gemm_gx(
    const ushort_t* __restrict__ z, const float* __restrict__ wf,
    const float* __restrict__ wb, const float* __restrict__ bfv,
    const float* __restrict__ bbv, ushort_t* __restrict__ gx2)
{
  __shared__ ushort_t As[128 * 40];
  __shared__ ushort_t Bs[64 * 40];
  int m0 = blockIdx.x * 128;          // m = s*64 + b (z is (s,b)-major)
  int n0g = blockIdx.y * 64;
  int dir = n0g >> 10;
  int ncol0 = n0g & 1023;
  const float* W = dir ? wb : wf;
  const float* bias = dir ? bbv : bfv;
  int tid = threadIdx.x;
  int wv = tid >> 6, l = tid & 63;
  int lm = l & 15, lq = l >> 4;
  v4f acc[2][4];
  #pragma unroll
  for (int i = 0; i < 2; i++)
    #pragma unroll
    for (int j = 0; j < 4; j++) acc[i][j] = (v4f)0.f;

  for (int kc = 0; kc < 10; ++kc) {
    int k0 = kc * 32;
    #pragma unroll
    for (int rep = 0; rep < 2; ++rep) {
      int idx = rep * 256 + tid;
      int row = idx >> 2, q = idx & 3;
      *(ui4*)(As + row*40 + q*8) =
          *(const ui4*)(z + (size_t)(m0 + row)*D_ + k0 + q*8);
    }
    {
      int row = tid >> 2, q = tid & 3;
      const float* src = W + (size_t)(ncol0 + row)*D_ + k0 + q*8;
      f4 a = *(const f4*)src, b2 = *(const f4*)(src + 4);
      us4 o0, o1;
      o0[0]=f2bf(a[0]); o0[1]=f2bf(a[1]); o0[2]=f2bf(a[2]); o0[3]=f2bf(a[3]);
      o1[0]=f2bf(b2[0]); o1[1]=f2bf(b2[1]); o1[2]=f2bf(b2[2]); o1[3]=f2bf(b2[3]);
      *(us4*)(Bs + row*40 + q*8) = o0;
      *(us4*)(Bs + row*40 + q*8 + 4) = o1;
    }
    __syncthreads();
    v8s a0 = *(const v8s*)(As + (wv*32 + lm)*40 + lq*8);
    v8s a1 = *(const v8s*)(As + (wv*32 + 16 + lm)*40 + lq*8);
    #pragma unroll
    for (int nt = 0; nt < 4; ++nt) {
      v8s b = *(const v8s*)(Bs + (nt*16 + lm)*40 + lq*8);
      acc[0][nt] = __builtin_amdgcn_mfma_f32_16x16x32_bf16(a0, b, acc[0][nt], 0, 0, 0);
      acc[1][nt] = __builtin_amdgcn_mfma_f32_16x16x32_bf16(a1, b, acc[1][nt], 0, 0, 0);
    }
    __syncthreads();
  }
  // epilogue: r spans 4 consecutive batches -> one aligned us4 store each
  float bval[4];
  #pragma unroll
  for (int nt = 0; nt < 4; nt++) bval[nt] = bias[ncol0 + nt*16 + lm];
  #pragma unroll
  for (int mt = 0; mt < 2; mt++)
    #pragma unroll
    for (int nt = 0; nt < 4; nt++) {
      int m = m0 + wv*32 + mt*16 + lq*4;   // + r
      int b = m & 63, s = m >> 6;
      int col = ncol0 + nt*16 + lm;
      int gate = col >> 8, unit = col & 255;
      int w2 = unit >> 5, j = (unit >> 4) & 1, lm2 = unit & 15;
      int bg = b >> 4, bl = b & 15;        // bl multiple of 4
      us4 o;
      #pragma unroll
      for (int r = 0; r < 4; r++) o[r] = f2bf(acc[mt][nt][r] + bval[nt]);
      size_t idx = ((size_t)(dir*512 + s)*4 + bg)*16384
                 + (size_t)(((w2*2 + j)*4 + gate)*16 + lm2)*16 + bl;
      *(us4*)(gx2 + idx) = o;
    }
}

// ---------------- K3: intra-CU persistent LSTM v4 -----------------------------------------------
// 8 blocks: dir(2) x bg(4, B=16). 8 waves; wave w owns units [32w,32w+32) x 4 gates.
// Two-pass acc (16 regs), acc init from gx, staggered g-prefetch, LDS-B kc-prefetch,
// coalesced hs dump from h LDS buffer. Target <=252 regs/wave -> no scratch spill.
__global__ __launch_bounds__(512, 2) void k_lstm(
    const ushort_t* __restrict__ gx2,
    const float* __restrict__ whhf, const float* __restrict__ whhb,
    ushort_t* __restrict__ hs)
{
  __shared__ ushort_t Wl[16 * 8 * 512];       // 128 KB
  __shared__ ushort_t hsh[2][16][PITCH];      // 17.5 KB
  int bid = blockIdx.x;
  int dir = bid >> 2, bg = bid & 3;
  int tid = threadIdx.x, w = tid >> 6, l = tid & 63;
  int lm = l & 15, lq = l >> 4;
  const float* W = dir ? whhb : whhf;

  for (int i = tid; i < 2 * 16 * PITCH; i += 512) ((ushort_t*)hsh)[i] = 0;
  // LDS W tiles: tile t=(w2,gsel): gate=2+gsel, rows gate*256 + w2*32 + 16 + lm2
  for (int idx = tid; idx < 16 * 8 * 64; idx += 512) {
    int t = idx >> 9, kc = (idx >> 6) & 7, ln = idx & 63;
    int lq2 = ln >> 4, lm2 = ln & 15;
    int w2 = t >> 1, gsel = t & 1;
    int row = (2 + gsel)*256 + w2*32 + 16 + lm2;
    const float* src = W + (size_t)row*256 + kc*32 + lq2*8;
    v8s f;
    #pragma unroll
    for (int jj = 0; jj < 8; jj++) f[jj] = (short)f2bf(src[jj]);
    *(v8s*)(Wl + ((size_t)(t*8 + kc)*64 + ln)*8) = f;
  }
  // register W tiles: ti 0..3 = gates i,f,g,o (lower 16 units); ti 4,5 = gates i,f (upper 16)
  v8s wfr[6][8];
  #pragma unroll
  for (int ti = 0; ti < 6; ti++) {
    int gate = (ti < 4) ? ti : (ti - 4);
    int jr = (ti < 4) ? 0 : 16;
    #pragma unroll
    for (int kc = 0; kc < 8; kc++) {
      const float* src = W + (size_t)(gate*256 + w*32 + jr + lm)*256 + kc*32 + lq*8;
      v8s f;
      #pragma unroll
      for (int jj = 0; jj < 8; jj++) f[jj] = (short)f2bf(src[jj]);
      wfr[ti][kc] = f;
    }
  }
  __syncthreads();

  float c0[4] = {0.f,0.f,0.f,0.f}, c1[4] = {0.f,0.f,0.f,0.f};
  int u0 = w*32 + lm, u1 = w*32 + 16 + lm;
  int goff[8];
  #pragma unroll
  for (int j = 0; j < 2; j++)
    #pragma unroll
    for (int ga = 0; ga < 4; ga++)
      goff[j*4 + ga] = (((w*2 + j)*4 + ga)*16 + lm)*16 + lq*4;
  // hs-dump lane mapping: one 16B slot per lane covers hsh[16][256]
  int db = tid >> 5, du = (tid & 31) * 8;

  us4 gA[4], gB[4];
  {
    int t0 = dir ? 511 : 0;
    const ushort_t* gb = gx2 + ((size_t)(dir*512 + t0)*4 + bg)*16384;
    #pragma unroll
    for (int k = 0; k < 4; k++) gA[k] = *(const us4*)(gb + goff[k]);
    #pragma unroll
    for (int k = 0; k < 4; k++) gB[k] = *(const us4*)(gb + goff[4 + k]);
  }

  for (int n = 0; n < 512; ++n) {
    int t = dir ? (511 - n) : n;
    const ushort_t* hrd = (const ushort_t*)hsh + (size_t)(n & 1)*16*PITCH;
    // coalesced dump of h_{t_prev} (stable read-parity buffer) to global hs
    if (n > 0) {
      int tp = dir ? (512 - n) : (n - 1);
      ui4 hv = *(const ui4*)(hrd + db*PITCH + du);
      *(ui4*)(hs + ((size_t)(dir*512 + tp)*64 + bg*16 + db)*256 + du) = hv;
    }
    const ushort_t* gnext = gx2
        + ((size_t)(dir*512 + (dir ? (511 - ((n < 511) ? n+1 : n)) : ((n < 511) ? n+1 : n)))*4 + bg)*16384;
    // ---- pass A: tiles 0..3 (gates i,f,g,o ; lower 16 units), acc init from gx ----
    v4f a0, a1, a2, a3;
    #pragma unroll
    for (int r = 0; r < 4; r++) {
      a0[r] = bf2f(gA[0][r]); a1[r] = bf2f(gA[1][r]);
      a2[r] = bf2f(gA[2][r]); a3[r] = bf2f(gA[3][r]);
    }
    {
      v8s A = *(const v8s*)(hrd + lm*PITCH + lq*8);
      #pragma unroll
      for (int kc = 0; kc < 8; kc++) {
        v8s An = (kc < 7) ? *(const v8s*)(hrd + lm*PITCH + (kc+1)*32 + lq*8) : A;
        a0 = __builtin_amdgcn_mfma_f32_16x16x32_bf16(A, wfr[0][kc], a0, 0, 0, 0);
        a1 = __builtin_amdgcn_mfma_f32_16x16x32_bf16(A, wfr[1][kc], a1, 0, 0, 0);
        a2 = __builtin_amdgcn_mfma_f32_16x16x32_bf16(A, wfr[2][kc], a2, 0, 0, 0);
        a3 = __builtin_amdgcn_mfma_f32_16x16x32_bf16(A, wfr[3][kc], a3, 0, 0, 0);
        A = An;
      }
    }
    ushort_t* hwr = (ushort_t*)hsh + (size_t)((n + 1) & 1)*16*PITCH;
    // ---- epi0 (units u0): VALU overlaps staggered waves' MFMA ----
    #pragma unroll
    for (int r = 0; r < 4; r++) {
      float ii = sigm(a0[r]), ff = sigm(a1[r]), gg = tanhp(a2[r]), oo = sigm(a3[r]);
      c0[r] = ff*c0[r] + ii*gg;
      hwr[(lq*4 + r)*PITCH + u0] = f2bf(oo * tanhp(c0[r]));
    }
    // prefetch next step's gA (long lead: passB + epi1 + barrier)
    #pragma unroll
    for (int k = 0; k < 4; k++) gA[k] = *(const us4*)(gnext + goff[k]);
    // ---- pass B: tiles 4,5 (reg: i,f upper) + LDS tiles (g,o upper) ----
    v4f a4, a5, a6, a7;
    #pragma unroll
    for (int r = 0; r < 4; r++) {
      a4[r] = bf2f(gB[0][r]); a5[r] = bf2f(gB[1][r]);
      a6[r] = bf2f(gB[2][r]); a7[r] = bf2f(gB[3][r]);
    }
    {
      v8s A = *(const v8s*)(hrd + lm*PITCH + lq*8);
      v8s B6 = *(const v8s*)(Wl + ((size_t)((w*2 + 0)*8 + 0)*64 + l)*8);
      v8s B7 = *(const v8s*)(Wl + ((size_t)((w*2 + 1)*8 + 0)*64 + l)*8);
      #pragma unroll
      for (int kc = 0; kc < 8; kc++) {
        v8s An = (kc < 7) ? *(const v8s*)(hrd + lm*PITCH + (kc+1)*32 + lq*8) : A;
        v8s B6n = (kc < 7) ? *(const v8s*)(Wl + ((size_t)((w*2 + 0)*8 + kc+1)*64 + l)*8) : B6;
        v8s B7n = (kc < 7) ? *(const v8s*)(Wl + ((size_t)((w*2 + 1)*8 + kc+1)*64 + l)*8) : B7;
        a4 = __builtin_amdgcn_mfma_f32_16x16x32_bf16(A, wfr[4][kc], a4, 0, 0, 0);
        a5 = __builtin_amdgcn_mfma_f32_16x16x32_bf16(A, wfr[5][kc], a5, 0, 0, 0);
        a6 = __builtin_amdgcn_mfma_f32_16x16x32_bf16(A, B6, a6, 0, 0, 0);
        a7 = __builtin_amdgcn_mfma_f32_16x16x32_bf16(A, B7, a7, 0, 0, 0);
        A = An; B6 = B6n; B7 = B7n;
      }
    }
    // ---- epi1 (units u1) ----
    #pragma unroll
    for (int r = 0; r < 4; r++) {
      float ii = sigm(a4[r]), ff = sigm(a5[r]), gg = tanhp(a6[r]), oo = sigm(a7[r]);
      c1[r] = ff*c1[r] + ii*gg;
      hwr[(lq*4 + r)*PITCH + u1] = f2bf(oo * tanhp(c1[r]));
    }
    // prefetch next step's gB (lead: barrier + dump + passA + epi0)
    #pragma unroll
    for (int k = 0; k < 4; k++) gB[k] = *(const us4*)(gnext + goff[4 + k]);
    block_sync_lds();   // lgkmcnt-only barrier: global loads/stores stay in flight
  }
  // final h dump: h at t_last lives in hsh[512&1 == 0]
  {
    int tp = dir ? 0 : 511;
    const ushort_t* hfin = (const ushort_t*)hsh;   // parity 0
    ui4 hv = *(const ui4*)(hfin + db*PITCH + du);
    *(ui4*)(hs + ((size_t)(dir*512 + tp)*64 + bg*16 + db)*256 + du) = hv;
  }
}

// ---------------- K4: emissions[b][s][17] = [h_f, h_b] @ cls_w^T + cls_b (fp32) ----------------
__global__ __launch_bounds__(256) void k_emis(
    const ushort_t* __restrict__ hs, const float* __restrict__ clsw,
    const float* __restrict__ clsb, float* __restrict__ emis)
{
  int tid = threadIdx.x;
  if (tid >= 255) return;
  int wi = blockIdx.x * 15 + tid / 17;
  int tau = tid % 17;
  if (wi >= B_ * S_) return;
  int b = wi >> 9, s = wi & 511;
  const ushort_t* hf  = hs + ((size_t)s*64 + b) * 256;
  const ushort_t* hbk = hs + (((size_t)512 + s)*64 + b) * 256;
  const float* cwf = clsw + (size_t)tau * 512;
  const float* cwb = cwf + 256;
  union { unsigned int u; float f; } bc;
  float acc = clsb[tau];
  for (int k = 0; k < 256; k += 4) {
    us4 h4 = *(const us4*)(hf + k); f4 w4 = *(const f4*)(cwf + k);
    #pragma unroll
    for (int j = 0; j < 4; j++) { bc.u = (unsigned int)h4[j] << 16; acc += bc.f * w4[j]; }
  }
  for (int k = 0; k < 256; k += 4) {
    us4 h4 = *(const us4*)(hbk + k); f4 w4 = *(const f4*)(cwb + k);
    #pragma unroll
    for (int j = 0; j < 4; j++) { bc.u = (unsigned int)h4[j] << 16; acc += bc.f * w4[j]; }
  }
  emis[(size_t)wi * 17 + tau] = acc;
}

// ---------------- K5: CRF — 64 blocks (one per batch): wave0 = loss fwd, wave1 = viterbi --------
__global__ __launch_bounds__(128) void k_crf(
    const float* __restrict__ emis, const int* __restrict__ labels,
    const int* __restrict__ mask, const float* __restrict__ startt,
    const float* __restrict__ endt, const float* __restrict__ trans,
    float* __restrict__ lossp, float* __restrict__ outp)
{
  __shared__ unsigned char bps[511][17];
  int b = blockIdx.x;
  int tid = threadIdx.x, wv = tid >> 6, l = tid & 63;
  int tauc = (l < 17) ? l : 0;
  float tc[17];
  #pragma unroll
  for (int i = 0; i < 17; i++) tc[i] = trans[i*17 + tauc];
  const float* eb = emis + (size_t)b * 512 * 17;
  float alpha = startt[tauc] + eb[tauc];
  if (l >= 17) alpha = -3e30f;

  if (wv == 0) {
    for (int t = 1; t < 512; t++) {
      float e = (l < 17) ? eb[t*17 + l] : 0.f;
      int mt = mask[b*512 + t];
      float arr[17]; float mx = -3e30f;
      #pragma unroll
      for (int i = 0; i < 17; i++) {
        float av = __shfl(alpha, i);
        arr[i] = av + tc[i];
        mx = fmaxf(mx, arr[i]);
      }
      float ss = 0.f;
      #pragma unroll
      for (int i = 0; i < 17; i++) ss += expf(arr[i] - mx);
      float nxt = mx + logf(ss) + e;
      if (mt > 0 && l < 17) alpha = nxt;
    }
    float a2 = (l < 17) ? (alpha + endt[l]) : -3e30f;
    float mx = a2;
    #pragma unroll
    for (int o = 32; o > 0; o >>= 1) mx = fmaxf(mx, __shfl_xor(mx, o));
    float ss = (l < 17) ? expf(a2 - mx) : 0.f;
    #pragma unroll
    for (int o = 32; o > 0; o >>= 1) ss += __shfl_xor(ss, o);
    float denom = mx + logf(ss);
    float ns = 0.f; int msum = 0;
    for (int t = l; t < 512; t += 64) {
      int tg = labels[b*512 + t];
      int mt = mask[b*512 + t];
      msum += (mt > 0);
      if (mt > 0) {
        ns += eb[t*17 + tg];
        if (t > 0) ns += trans[labels[b*512 + t - 1]*17 + tg];
      }
    }
    #pragma unroll
    for (int o = 32; o > 0; o >>= 1) { ns += __shfl_xor(ns, o); msum += __shfl_xor(msum, o); }
    if (l == 0) {
      int lidx = msum - 1;
      float num = ns + startt[labels[b*512]] + endt[labels[b*512 + lidx]];
      lossp[b] = num - denom;
    }
  } else {
    for (int t = 1; t < 512; t++) {
      float e = (l < 17) ? eb[t*17 + l] : 0.f;
      int mt = mask[b*512 + t];
      float best = -3e30f; int bi = 0;
      #pragma unroll
      for (int i = 0; i < 17; i++) {
        float v = __shfl(alpha, i) + tc[i];
        if (v > best) { best = v; bi = i; }   // first-max tie-break = np.argmax
      }
      float nxt = best + e;
      int bpv = (mt > 0) ? bi : l;
      if (l < 17) {
        bps[t-1][l] = (unsigned char)bpv;
        if (mt > 0) alpha = nxt;
      }
    }
    float a2 = (l < 17) ? (alpha + endt[l]) : -3e30f;
    float av[17];
    #pragma unroll
    for (int i = 0; i < 17; i++) av[i] = __shfl(a2, i);
    int bt = 0; float bv2 = av[0];
    #pragma unroll
    for (int i = 1; i < 17; i++) if (av[i] > bv2) { bv2 = av[i]; bt = i; }
    if (l == 0) outp[1 + b*512 + 511] = (float)bt;
    int tg = bt;
    for (int t = 510; t >= 0; --t) {
      tg = bps[t][tg];
      if (l == 0) outp[1 + b*512 + t] = (float)tg;
    }
  }
}

// ---------------- K6: loss = -mean(num - denom), fp32 ----------------
__global__ __launch_bounds__(64) void k_final(const float* __restrict__ lossp,
                                              float* __restrict__ outp)
{
  int l = threadIdx.x;
  float v = lossp[l];
  #pragma unroll
  for (int o = 32; o > 0; o >>= 1) v += __shfl_xor(v, o);
  if (l == 0) outp[0] = -(v / 64.f);
}

// ---------------- host ----------------
extern "C" void kernel_launch(void* const* d_in, const int* in_sizes, int n_in,
                              void* d_out, int out_size, void* d_ws, size_t ws_size,
                              hipStream_t stream)
{
  (void)in_sizes; (void)n_in; (void)out_size; (void)ws_size;
  const int*   tok   = (const int*)d_in[0];
  const int*   ctok  = (const int*)d_in[1];
  const int*   labels= (const int*)d_in[2];
  const int*   amask = (const int*)d_in[3];
  const float* wemb  = (const float*)d_in[4];
  const float* cemb  = (const float*)d_in[5];
  const float* convw = (const float*)d_in[6];
  const float* convb = (const float*)d_in[7];
  const float* wihf  = (const float*)d_in[8];
  const float* whhf  = (const float*)d_in[9];
  const float* bfv   = (const float*)d_in[10];
  const float* wihb  = (const float*)d_in[11];
  const float* whhb  = (const float*)d_in[12];
  const float* bbv   = (const float*)d_in[13];
  const float* clsw  = (const float*)d_in[14];
  const float* clsb  = (const float*)d_in[15];
  const float* stt   = (const float*)d_in[16];
  const float* ent   = (const float*)d_in[17];
  const float* trn   = (const float*)d_in[18];

  // workspace layout (bytes): [z 20,971,520][gx2 134,217,728][hs 33,554,432]
  //                           [emis 2,228,224][lossp 256]
  char* ws = (char*)d_ws;
  ushort_t* z    = (ushort_t*)(ws);
  ushort_t* gx2  = (ushort_t*)(ws + 20971520);
  ushort_t* hs   = (ushort_t*)(ws + 155189248);
  float*    emis = (float*)(ws + 188743680);
  float*    lossp= (float*)(ws + 190971904);

  hipLaunchKernelGGL(k_embed,   dim3(B_*S_),       dim3(64),  0, stream,
                     tok, ctok, wemb, cemb, convw, convb, z);
  hipLaunchKernelGGL(k_gemm_gx, dim3(256, 32),     dim3(256), 0, stream,
                     z, wihf, wihb, bfv, bbv, gx2);
  hipLaunchKernelGGL(k_lstm,    dim3(8),           dim3(512), 0, stream,
                     gx2, whhf, whhb, hs);
  hipLaunchKernelGGL(k_emis,    dim3((B_*S_ + 14)/15), dim3(256), 0, stream,
                     hs, clsw, clsb, emis);
  hipLaunchKernelGGL(k_crf,     dim3(64),          dim3(128), 0, stream,
                     emis, labels, amask, stt, ent, trn, lossp, (float*)d_out);
  hipLaunchKernelGGL(k_final,   dim3(1),           dim3(64),  0, stream,
                     lossp, (float*)d_out);
}